// Round 4
// baseline (431.343 us; speedup 1.0000x reference)
//
#include <hip/hip_runtime.h>
#include <math.h>

#define NRED_BLOCKS 256
#define THREADS 256
#define MAX_N 400000

struct SmallState {
    float meanf[3];
    float inv_sf;
    float Qf[12][3];
    double Qd[12][3];
};

// All scratch in module-scope device globals: zero dependence on ws_size.
// Every element read is written earlier in the same kernel_launch call.
__device__ SmallState g_sm;
__device__ double g_statsPart[NRED_BLOCKS * 6];
__device__ double g_redPart[NRED_BLOCKS * 48];
__device__ float g_ca[(size_t)MAX_N * 3];

__device__ inline float waveReduceAdd(float v) {
#pragma unroll
    for (int off = 32; off > 0; off >>= 1) v += __shfl_down(v, off, 64);
    return v;
}

// Pass 1: extract CA atoms (xyz[:,1,:]), accumulate per-column sum & sumsq,
// compact CA coords into g_ca for the iteration passes.
__global__ void k_extract(const float* __restrict__ xyz, int N, int storeCA) {
    int tid = threadIdx.x;
    int gid = blockIdx.x * blockDim.x + tid;
    int gsz = gridDim.x * blockDim.x;
    float s0 = 0, s1 = 0, s2 = 0, q0 = 0, q1 = 0, q2 = 0;
    for (int j = gid; j < N; j += gsz) {
        size_t base = (size_t)j * 81 + 3;
        float x = xyz[base + 0], y = xyz[base + 1], z = xyz[base + 2];
        s0 += x; s1 += y; s2 += z;
        q0 += x * x; q1 += y * y; q2 += z * z;
        if (storeCA) {
            g_ca[(size_t)j * 3 + 0] = x;
            g_ca[(size_t)j * 3 + 1] = y;
            g_ca[(size_t)j * 3 + 2] = z;
        }
    }
    float v[6] = {s0, s1, s2, q0, q1, q2};
#pragma unroll
    for (int k = 0; k < 6; k++) v[k] = waveReduceAdd(v[k]);
    __shared__ float part[4][6];
    int wave = tid >> 6, lane = tid & 63;
    if (lane == 0) {
#pragma unroll
        for (int k = 0; k < 6; k++) part[wave][k] = v[k];
    }
    __syncthreads();
    if (tid == 0) {
#pragma unroll
        for (int k = 0; k < 6; k++) {
            double d = (double)part[0][k] + part[1][k] + part[2][k] + part[3][k];
            g_statsPart[blockIdx.x * 6 + k] = d;
        }
    }
}

// Pass 2: finalize mean/std of binder CA; normalize zdna_ref -> Q0.
__global__ void k_init(const float* __restrict__ zdna, int N) {
    __shared__ double tot[6];
    int tid = threadIdx.x;
    if (tid < 6) {
        double s = 0;
        for (int b = 0; b < NRED_BLOCKS; b++) s += g_statsPart[b * 6 + tid];
        tot[tid] = s;
    }
    __syncthreads();
    if (tid != 0) return;
    double mean[3];
    double stdsum = 0;
    for (int c = 0; c < 3; c++) {
        mean[c] = tot[c] / (double)N;
        double var = (tot[3 + c] - (double)N * mean[c] * mean[c]) / (double)(N - 1);
        stdsum += sqrt(fmax(var, 0.0));
    }
    double s = fmax(stdsum / 3.0, 1e-6);
    double inv = 1.0 / s;
    for (int c = 0; c < 3; c++) g_sm.meanf[c] = (float)mean[c];
    g_sm.inv_sf = (float)inv;

    // zdna normalization (12 points)
    double z[12][3], zm[3] = {0, 0, 0};
    for (int i = 0; i < 12; i++)
        for (int c = 0; c < 3; c++) {
            z[i][c] = (double)zdna[i * 3 + c];
            zm[c] += z[i][c];
        }
    for (int c = 0; c < 3; c++) zm[c] /= 12.0;
    double zvar[3] = {0, 0, 0};
    for (int i = 0; i < 12; i++)
        for (int c = 0; c < 3; c++) {
            z[i][c] -= zm[c];
            zvar[c] += z[i][c] * z[i][c];
        }
    double zs = 0;
    for (int c = 0; c < 3; c++) zs += sqrt(zvar[c] / 11.0);
    zs = fmax(zs / 3.0, 1e-6);
    double zinv = 1.0 / zs;
    for (int i = 0; i < 12; i++)
        for (int c = 0; c < 3; c++) {
            double q = z[i][c] * zinv;
            g_sm.Qd[i][c] = q;
            g_sm.Qf[i][c] = (float)q;
        }
}

// Per-iteration big reduction: S_i = sum_j w_ij ; T_i = sum_j w_ij * p_j
// (row-sum normalization folded in analytically downstream)
__global__ void k_reduce(const float* __restrict__ srcArg, int stride, int N,
                         int useCA) {
    const float* src = useCA ? (const float*)g_ca : srcArg;  // uniform select
    const float inv2s2 = 1.0f / 50.000001f;  // 1/(2*sigma^2 + 1e-6), sigma=5
    int tid = threadIdx.x;
    int gid = blockIdx.x * blockDim.x + tid;
    int gsz = gridDim.x * blockDim.x;
    float mx = g_sm.meanf[0], my = g_sm.meanf[1], mz = g_sm.meanf[2];
    float inv = g_sm.inv_sf;
    float qx[12], qy[12], qz[12], q2[12];
#pragma unroll
    for (int i = 0; i < 12; i++) {
        qx[i] = g_sm.Qf[i][0];
        qy[i] = g_sm.Qf[i][1];
        qz[i] = g_sm.Qf[i][2];
        q2[i] = qx[i] * qx[i] + qy[i] * qy[i] + qz[i] * qz[i];
    }
    float S[12], Tx[12], Ty[12], Tz[12];
#pragma unroll
    for (int i = 0; i < 12; i++) { S[i] = 0; Tx[i] = 0; Ty[i] = 0; Tz[i] = 0; }
    for (int j = gid; j < N; j += gsz) {
        size_t b = (size_t)j * (size_t)stride;
        float px = (src[b + 0] - mx) * inv;
        float py = (src[b + 1] - my) * inv;
        float pz = (src[b + 2] - mz) * inv;
        float pp = px * px + py * py + pz * pz;
#pragma unroll
        for (int i = 0; i < 12; i++) {
            float d2 = q2[i] + pp - 2.0f * (qx[i] * px + qy[i] * py + qz[i] * pz);
            d2 = fmaxf(d2, 0.0f);
            float w = __expf(-d2 * inv2s2);
            S[i] += w;
            Tx[i] += w * px;
            Ty[i] += w * py;
            Tz[i] += w * pz;
        }
    }
    float acc[48];
#pragma unroll
    for (int i = 0; i < 12; i++) {
        acc[i] = S[i];
        acc[12 + i] = Tx[i];
        acc[24 + i] = Ty[i];
        acc[36 + i] = Tz[i];
    }
#pragma unroll
    for (int k = 0; k < 48; k++) acc[k] = waveReduceAdd(acc[k]);
    __shared__ float part[4][48];
    int wave = tid >> 6, lane = tid & 63;
    if (lane == 0) {
#pragma unroll
        for (int k = 0; k < 48; k++) part[wave][k] = acc[k];
    }
    __syncthreads();
    if (tid < 48) {
        double d = (double)part[0][tid] + part[1][tid] + part[2][tid] + part[3][tid];
        g_redPart[blockIdx.x * 48 + tid] = d;
    }
}

// Per-iteration tiny Kabsch: reduce block partials, f64 SVD, update Q, rmsd.
__global__ void k_kabsch(float* __restrict__ out, int last) {
    __shared__ double dsum[48];
    int tid = threadIdx.x;
    if (tid < 48) {
        double s = 0;
        for (int b = 0; b < NRED_BLOCKS; b++) s += g_redPart[b * 48 + tid];
        dsum[tid] = s;
    }
    __syncthreads();
    if (tid != 0) return;

    double S[12], Tv[12][3], Q[12][3];
    for (int i = 0; i < 12; i++) {
        S[i] = dsum[i];
        Tv[i][0] = dsum[12 + i];
        Tv[i][1] = dsum[24 + i];
        Tv[i][2] = dsum[36 + i];
        for (int c = 0; c < 3; c++) Q[i][c] = g_sm.Qd[i][c];
    }
    double n[12], wsum = 0;
    for (int i = 0; i < 12; i++) {
        n[i] = 1.0 / (S[i] + 1e-6);
        wsum += S[i] * n[i];
    }
    wsum = fmax(wsum, 1e-6);
    double cP[3] = {0, 0, 0}, cQ[3] = {0, 0, 0};
    for (int i = 0; i < 12; i++)
        for (int c = 0; c < 3; c++) {
            cP[c] += n[i] * Tv[i][c];
            cQ[c] += S[i] * n[i] * Q[i][c];
        }
    for (int c = 0; c < 3; c++) { cP[c] /= wsum; cQ[c] /= wsum; }

    double H[3][3] = {{0, 0, 0}, {0, 0, 0}, {0, 0, 0}};
    for (int i = 0; i < 12; i++) {
        double ta[3];
        for (int a = 0; a < 3; a++) ta[a] = n[i] * (Tv[i][a] - S[i] * cP[a]);
        for (int a = 0; a < 3; a++)
            for (int b = 0; b < 3; b++) H[a][b] += ta[a] * (Q[i][b] - cQ[b]);
    }
    for (int a = 0; a < 3; a++) H[a][a] += 1e-6;

    // Jacobi eigendecomposition of A = H^T H -> right singular vectors V
    double A[3][3], V[3][3];
    for (int a = 0; a < 3; a++)
        for (int b = 0; b < 3; b++) {
            double s = 0;
            for (int k = 0; k < 3; k++) s += H[k][a] * H[k][b];
            A[a][b] = s;
            V[a][b] = (a == b) ? 1.0 : 0.0;
        }
    for (int sweep = 0; sweep < 8; sweep++) {
        for (int p = 0; p < 2; p++)
            for (int q = p + 1; q < 3; q++) {
                double apq = A[p][q];
                if (fabs(apq) < 1e-300) continue;
                double theta = (A[q][q] - A[p][p]) / (2.0 * apq);
                double t = copysign(1.0, theta) / (fabs(theta) + sqrt(theta * theta + 1.0));
                double c = 1.0 / sqrt(t * t + 1.0);
                double s = t * c;
                A[p][p] = A[p][p] - t * apq;
                A[q][q] = A[q][q] + t * apq;
                A[p][q] = 0; A[q][p] = 0;
                int r = 3 - p - q;
                double arp = A[r][p], arq = A[r][q];
                A[r][p] = A[p][r] = c * arp - s * arq;
                A[r][q] = A[q][r] = s * arp + c * arq;
                for (int k = 0; k < 3; k++) {
                    double vkp = V[k][p], vkq = V[k][q];
                    V[k][p] = c * vkp - s * vkq;
                    V[k][q] = s * vkp + c * vkq;
                }
            }
    }
    // U columns: u_k = H v_k / sigma_k ; R = V U^T  (== Vh.T @ U.T)
    double U[3][3];
    for (int k = 0; k < 3; k++) {
        double sig = sqrt(fmax(A[k][k], 0.0));
        double u[3];
        for (int a = 0; a < 3; a++)
            u[a] = H[a][0] * V[0][k] + H[a][1] * V[1][k] + H[a][2] * V[2][k];
        double invsig = 1.0 / fmax(sig, 1e-30);
        for (int a = 0; a < 3; a++) U[a][k] = u[a] * invsig;
    }
    double R[3][3];
    for (int a = 0; a < 3; a++)
        for (int b = 0; b < 3; b++)
            R[a][b] = V[a][0] * U[b][0] + V[a][1] * U[b][1] + V[a][2] * U[b][2];
    double det = R[0][0] * (R[1][1] * R[2][2] - R[1][2] * R[2][1])
               - R[0][1] * (R[1][0] * R[2][2] - R[1][2] * R[2][0])
               + R[0][2] * (R[1][0] * R[2][1] - R[1][1] * R[2][0]);
    if (det < 0)
        for (int a = 0; a < 3; a++)
            for (int b = 0; b < 3; b++) R[a][b] = -R[a][b];
    double t[3];
    for (int b = 0; b < 3; b++)
        t[b] = cQ[b] - (cP[0] * R[0][b] + cP[1] * R[1][b] + cP[2] * R[2][b]);

    double res2 = 0;
    for (int i = 0; i < 12; i++) {
        double qn[3];
        for (int b = 0; b < 3; b++) {
            qn[b] = Q[i][0] * R[0][b] + Q[i][1] * R[1][b] + Q[i][2] * R[2][b] + t[b];
            double diff = qn[b] - n[i] * Tv[i][b];
            res2 += diff * diff;
        }
        for (int b = 0; b < 3; b++) {
            g_sm.Qd[i][b] = qn[b];
            g_sm.Qf[i][b] = (float)qn[b];
        }
    }
    double rmsd = sqrt(res2 / 12.0 + 1e-6);
    if (last) out[0] = (float)(-10.0 * rmsd);
}

extern "C" void kernel_launch(void* const* d_in, const int* in_sizes, int n_in,
                              void* d_out, int out_size, void* d_ws, size_t ws_size,
                              hipStream_t stream) {
    (void)d_ws; (void)ws_size;
    const float* xyz = (const float*)d_in[0];
    const float* zdna = (const float*)d_in[1];
    int N = in_sizes[0] / 81;  // points (binderlen), CA at atom index 1 of 27
    int useCA = (N <= MAX_N) ? 1 : 0;
    float* out = (float*)d_out;

    hipLaunchKernelGGL(k_extract, dim3(NRED_BLOCKS), dim3(THREADS), 0, stream,
                       xyz, N, useCA);
    hipLaunchKernelGGL(k_init, dim3(1), dim3(64), 0, stream, zdna, N);

    const float* src = useCA ? (const float*)nullptr : (xyz + 3);
    int stride = useCA ? 3 : 81;
    for (int it = 0; it < 10; ++it) {
        hipLaunchKernelGGL(k_reduce, dim3(NRED_BLOCKS), dim3(THREADS), 0, stream,
                           src, stride, N, useCA);
        hipLaunchKernelGGL(k_kabsch, dim3(1), dim3(64), 0, stream,
                           out, (it == 9) ? 1 : 0);
    }
}

// Round 7
// 428.778 us; speedup vs baseline: 1.0060x; 1.0060x over previous
//
#include <hip/hip_runtime.h>
#include <math.h>

#define NBLK 256
#define THREADS 256
#define MAX_N 400000

struct SmallState {
    float meanf[3];
    float inv_sf;
    float Qf[12][3];
    double Qd[12][3];
};

// Device-global scratch (no ws_size dependence). g_ctr self-resets each call;
// everything else is written before read within each call.
__device__ SmallState g_sm;
__device__ double g_part[NBLK * 48];
__device__ int g_ctr[16] = {};  // zero-init at load; last block resets after use
__device__ float g_cax[MAX_N];
__device__ float g_cay[MAX_N];
__device__ float g_caz[MAX_N];

__device__ inline float waveReduceAdd(float v) {
#pragma unroll
    for (int off = 32; off > 0; off >>= 1) v += __shfl_down(v, off, 64);
    return v;
}

__device__ inline void partStore(double* p, double v) {
    __hip_atomic_store(p, v, __ATOMIC_RELAXED, __HIP_MEMORY_SCOPE_AGENT);
}
__device__ inline double partLoad(const double* p) {
    return __hip_atomic_load(p, __ATOMIC_RELAXED, __HIP_MEMORY_SCOPE_AGENT);
}

// Returns true in exactly one block (the last to arrive), after all blocks'
// agent-scope partial stores are visible.
__device__ inline bool lastBlockArrives(int slot) {
    __shared__ int s_last;
    __syncthreads();
    if (threadIdx.x == 0) {
        __threadfence();
        int prev = atomicAdd(&g_ctr[slot], 1);
        s_last = (prev == NBLK - 1) ? 1 : 0;
    }
    __syncthreads();
    if (!s_last) return false;
    __threadfence();
    return true;
}

// Full f64 weighted-Kabsch tail (verified absmax 0.0 in round 4).
// dsum[48] = {S[12], Tx[12], Ty[12], Tz[12]} grid totals.
__device__ void kabschUpdate(const double* __restrict__ dsum,
                             float* __restrict__ out, int it) {
    double S[12], Tv[12][3], Q[12][3];
    for (int i = 0; i < 12; i++) {
        S[i] = dsum[i];
        Tv[i][0] = dsum[12 + i];
        Tv[i][1] = dsum[24 + i];
        Tv[i][2] = dsum[36 + i];
        for (int c = 0; c < 3; c++) Q[i][c] = g_sm.Qd[i][c];
    }
    double n[12], wsum = 0;
    for (int i = 0; i < 12; i++) {
        n[i] = 1.0 / (S[i] + 1e-6);
        wsum += S[i] * n[i];
    }
    wsum = fmax(wsum, 1e-6);
    double cP[3] = {0, 0, 0}, cQ[3] = {0, 0, 0};
    for (int i = 0; i < 12; i++)
        for (int c = 0; c < 3; c++) {
            cP[c] += n[i] * Tv[i][c];
            cQ[c] += S[i] * n[i] * Q[i][c];
        }
    for (int c = 0; c < 3; c++) { cP[c] /= wsum; cQ[c] /= wsum; }

    double H[3][3] = {{0, 0, 0}, {0, 0, 0}, {0, 0, 0}};
    for (int i = 0; i < 12; i++) {
        double ta[3];
        for (int a = 0; a < 3; a++) ta[a] = n[i] * (Tv[i][a] - S[i] * cP[a]);
        for (int a = 0; a < 3; a++)
            for (int b = 0; b < 3; b++) H[a][b] += ta[a] * (Q[i][b] - cQ[b]);
    }
    for (int a = 0; a < 3; a++) H[a][a] += 1e-6;

    // Jacobi on A = H^T H -> V (right singular vectors)
    double A[3][3], V[3][3];
    for (int a = 0; a < 3; a++)
        for (int b = 0; b < 3; b++) {
            double s = 0;
            for (int k = 0; k < 3; k++) s += H[k][a] * H[k][b];
            A[a][b] = s;
            V[a][b] = (a == b) ? 1.0 : 0.0;
        }
    for (int sweep = 0; sweep < 8; sweep++) {
        for (int p = 0; p < 2; p++)
            for (int q = p + 1; q < 3; q++) {
                double apq = A[p][q];
                if (fabs(apq) < 1e-300) continue;
                double theta = (A[q][q] - A[p][p]) / (2.0 * apq);
                double t = copysign(1.0, theta) / (fabs(theta) + sqrt(theta * theta + 1.0));
                double c = 1.0 / sqrt(t * t + 1.0);
                double s = t * c;
                A[p][p] = A[p][p] - t * apq;
                A[q][q] = A[q][q] + t * apq;
                A[p][q] = 0; A[q][p] = 0;
                int r = 3 - p - q;
                double arp = A[r][p], arq = A[r][q];
                A[r][p] = A[p][r] = c * arp - s * arq;
                A[r][q] = A[q][r] = s * arp + c * arq;
                for (int k = 0; k < 3; k++) {
                    double vkp = V[k][p], vkq = V[k][q];
                    V[k][p] = c * vkp - s * vkq;
                    V[k][q] = s * vkp + c * vkq;
                }
            }
    }
    double U[3][3];
    for (int k = 0; k < 3; k++) {
        double sig = sqrt(fmax(A[k][k], 0.0));
        double u[3];
        for (int a = 0; a < 3; a++)
            u[a] = H[a][0] * V[0][k] + H[a][1] * V[1][k] + H[a][2] * V[2][k];
        double invsig = 1.0 / fmax(sig, 1e-30);
        for (int a = 0; a < 3; a++) U[a][k] = u[a] * invsig;
    }
    double R[3][3];
    for (int a = 0; a < 3; a++)
        for (int b = 0; b < 3; b++)
            R[a][b] = V[a][0] * U[b][0] + V[a][1] * U[b][1] + V[a][2] * U[b][2];
    double det = R[0][0] * (R[1][1] * R[2][2] - R[1][2] * R[2][1])
               - R[0][1] * (R[1][0] * R[2][2] - R[1][2] * R[2][0])
               + R[0][2] * (R[1][0] * R[2][1] - R[1][1] * R[2][0]);
    if (det < 0)
        for (int a = 0; a < 3; a++)
            for (int b = 0; b < 3; b++) R[a][b] = -R[a][b];
    double tr[3];
    for (int b = 0; b < 3; b++)
        tr[b] = cQ[b] - (cP[0] * R[0][b] + cP[1] * R[1][b] + cP[2] * R[2][b]);

    double res2 = 0;
    for (int i = 0; i < 12; i++) {
        double qn[3];
        for (int b = 0; b < 3; b++) {
            qn[b] = Q[i][0] * R[0][b] + Q[i][1] * R[1][b] + Q[i][2] * R[2][b] + tr[b];
            double diff = qn[b] - n[i] * Tv[i][b];
            res2 += diff * diff;
        }
        for (int b = 0; b < 3; b++) {
            g_sm.Qd[i][b] = qn[b];
            g_sm.Qf[i][b] = (float)qn[b];
        }
    }
    if (it == 9) {
        double rmsd = sqrt(res2 / 12.0 + 1e-6);
        out[0] = (float)(-10.0 * rmsd);
    }
}

// Kernel 1: extract CA (xyz[:,1,:]) into planar g_ca*, per-column stats;
// last block finalizes mean/std + normalizes zdna -> g_sm.
__global__ void __launch_bounds__(THREADS)
k_extract(const float* __restrict__ xyz, const float* __restrict__ zdna,
          int N, int chunk) {
    const int tid = threadIdx.x, bid = blockIdx.x;
    const int start = bid * chunk;
    const int lim = (start + chunk < N) ? (start + chunk) : N;

    float s0 = 0, s1 = 0, s2 = 0, q0 = 0, q1 = 0, q2 = 0;
    for (int j = start + tid; j < lim; j += THREADS) {
        size_t base = (size_t)j * 81 + 3;
        float x = xyz[base + 0], y = xyz[base + 1], z = xyz[base + 2];
        g_cax[j] = x; g_cay[j] = y; g_caz[j] = z;
        s0 += x; s1 += y; s2 += z;
        q0 += x * x; q1 += y * y; q2 += z * z;
    }
    {
        float v[6] = {s0, s1, s2, q0, q1, q2};
#pragma unroll
        for (int k = 0; k < 6; k++) v[k] = waveReduceAdd(v[k]);
        __shared__ double p6[4][6];
        int wave = tid >> 6, lane = tid & 63;
        if (lane == 0) {
#pragma unroll
            for (int k = 0; k < 6; k++) p6[wave][k] = (double)v[k];
        }
        __syncthreads();
        if (tid < 6)
            partStore(&g_part[bid * 48 + tid],
                      p6[0][tid] + p6[1][tid] + p6[2][tid] + p6[3][tid]);
    }
    if (!lastBlockArrives(10)) return;

    // Tail: parallel stats sum (6 cols x 256 rows, 4-way unrolled)
    __shared__ double tot[6];
    if (tid < 6) {
        double a0 = 0, a1 = 0, a2 = 0, a3 = 0;
#pragma unroll 4
        for (int b = 0; b < NBLK; b += 4) {
            a0 += partLoad(&g_part[(b + 0) * 48 + tid]);
            a1 += partLoad(&g_part[(b + 1) * 48 + tid]);
            a2 += partLoad(&g_part[(b + 2) * 48 + tid]);
            a3 += partLoad(&g_part[(b + 3) * 48 + tid]);
        }
        tot[tid] = (a0 + a1) + (a2 + a3);
    }
    __syncthreads();
    if (tid == 0) {
        double mean[3], stdsum = 0;
        for (int c = 0; c < 3; c++) {
            mean[c] = tot[c] / (double)N;
            double var = (tot[3 + c] - (double)N * mean[c] * mean[c]) / (double)(N - 1);
            stdsum += sqrt(fmax(var, 0.0));
        }
        double sdev = fmax(stdsum / 3.0, 1e-6);
        double inv = 1.0 / sdev;
        for (int c = 0; c < 3; c++) g_sm.meanf[c] = (float)mean[c];
        g_sm.inv_sf = (float)inv;

        double z[12][3], zm[3] = {0, 0, 0};
        for (int i = 0; i < 12; i++)
            for (int c = 0; c < 3; c++) {
                z[i][c] = (double)zdna[i * 3 + c];
                zm[c] += z[i][c];
            }
        for (int c = 0; c < 3; c++) zm[c] /= 12.0;
        double zvar[3] = {0, 0, 0};
        for (int i = 0; i < 12; i++)
            for (int c = 0; c < 3; c++) {
                z[i][c] -= zm[c];
                zvar[c] += z[i][c] * z[i][c];
            }
        double zs = 0;
        for (int c = 0; c < 3; c++) zs += sqrt(zvar[c] / 11.0);
        zs = fmax(zs / 3.0, 1e-6);
        double zinv = 1.0 / zs;
        for (int i = 0; i < 12; i++)
            for (int c = 0; c < 3; c++) {
                double q = z[i][c] * zinv;
                g_sm.Qd[i][c] = q;
                g_sm.Qf[i][c] = (float)q;
            }
        g_ctr[10] = 0;  // self-reset for next call
    }
}

// Kernel 2 (x10): soft-assign reduction + last-block Kabsch.
__global__ void __launch_bounds__(THREADS)
k_iter(float* __restrict__ out, int N, int chunk, int it) {
    const int tid = threadIdx.x, bid = blockIdx.x;
    const int start = bid * chunk;
    const int lim = (start + chunk < N) ? (start + chunk) : N;
    const float inv2s2 = 1.0f / 50.000001f;  // 1/(2*sigma^2+1e-6), sigma=5

    const float mx = g_sm.meanf[0], my = g_sm.meanf[1], mz = g_sm.meanf[2];
    const float inv = g_sm.inv_sf;
    float qx[12], qy[12], qz[12], qq[12];
#pragma unroll
    for (int i = 0; i < 12; i++) {
        qx[i] = g_sm.Qf[i][0];
        qy[i] = g_sm.Qf[i][1];
        qz[i] = g_sm.Qf[i][2];
        qq[i] = qx[i] * qx[i] + qy[i] * qy[i] + qz[i] * qz[i];
    }
    float S[12], Tx[12], Ty[12], Tz[12];
#pragma unroll
    for (int i = 0; i < 12; i++) { S[i] = 0; Tx[i] = 0; Ty[i] = 0; Tz[i] = 0; }

    for (int j = start + tid; j < lim; j += THREADS) {
        float x = (g_cax[j] - mx) * inv;
        float y = (g_cay[j] - my) * inv;
        float z = (g_caz[j] - mz) * inv;
        float pp = x * x + y * y + z * z;
#pragma unroll
        for (int i = 0; i < 12; i++) {
            float d2 = qq[i] + pp - 2.0f * (qx[i] * x + qy[i] * y + qz[i] * z);
            d2 = fmaxf(d2, 0.0f);
            float w = __expf(-d2 * inv2s2);
            S[i] += w;
            Tx[i] += w * x;
            Ty[i] += w * y;
            Tz[i] += w * z;
        }
    }
    {
        float acc[48];
#pragma unroll
        for (int i = 0; i < 12; i++) {
            acc[i] = S[i]; acc[12 + i] = Tx[i]; acc[24 + i] = Ty[i]; acc[36 + i] = Tz[i];
        }
#pragma unroll
        for (int k = 0; k < 48; k++) acc[k] = waveReduceAdd(acc[k]);
        __shared__ double p48[4][48];
        int wave = tid >> 6, lane = tid & 63;
        if (lane == 0) {
#pragma unroll
            for (int k = 0; k < 48; k++) p48[wave][k] = (double)acc[k];
        }
        __syncthreads();
        if (tid < 48)
            partStore(&g_part[bid * 48 + tid],
                      p48[0][tid] + p48[1][tid] + p48[2][tid] + p48[3][tid]);
    }
    if (!lastBlockArrives(it)) return;

    // Tail: parallel column sum (48 cols x 256 rows -> 4 segs of 64, unrolled)
    __shared__ double red[4][48];
    if (tid < 192) {
        int col = tid % 48, seg = tid / 48;
        int b0 = seg * 64;
        double a0 = 0, a1 = 0, a2 = 0, a3 = 0;
#pragma unroll 4
        for (int b = b0; b < b0 + 64; b += 4) {
            a0 += partLoad(&g_part[(b + 0) * 48 + col]);
            a1 += partLoad(&g_part[(b + 1) * 48 + col]);
            a2 += partLoad(&g_part[(b + 2) * 48 + col]);
            a3 += partLoad(&g_part[(b + 3) * 48 + col]);
        }
        red[seg][col] = (a0 + a1) + (a2 + a3);
    }
    __syncthreads();
    __shared__ double dsum[48];
    if (tid < 48)
        dsum[tid] = (red[0][tid] + red[1][tid]) + (red[2][tid] + red[3][tid]);
    __syncthreads();
    if (tid == 0) {
        kabschUpdate(dsum, out, it);
        g_ctr[it] = 0;  // self-reset for next call
    }
}

extern "C" void kernel_launch(void* const* d_in, const int* in_sizes, int n_in,
                              void* d_out, int out_size, void* d_ws, size_t ws_size,
                              hipStream_t stream) {
    (void)d_ws; (void)ws_size;
    const float* xyz = (const float*)d_in[0];
    const float* zdna = (const float*)d_in[1];
    int N = in_sizes[0] / 81;  // CA at atom index 1 of 27
    int chunk = (N + NBLK - 1) / NBLK;
    float* out = (float*)d_out;

    hipLaunchKernelGGL(k_extract, dim3(NBLK), dim3(THREADS), 0, stream,
                       xyz, zdna, N, chunk);
    for (int it = 0; it < 10; ++it)
        hipLaunchKernelGGL(k_iter, dim3(NBLK), dim3(THREADS), 0, stream,
                           out, N, chunk, it);
}